// Round 8
// baseline (342.896 us; speedup 1.0000x reference)
//
#include <hip/hip_runtime.h>
#include <hip/hip_bf16.h>

namespace {

constexpr int B_   = 4;
constexpr int CIN  = 64;
constexpr int COUT = 128;
constexpr int HIN  = 64,  WIN  = 1024;
constexpr int HOUT = 32,  WOUT = 512;
constexpr int TW   = 16;        // wo positions per K1 block
constexpr int KTOT = CIN * 16;  // 1024
constexpr int NPOS = B_ * HOUT * WOUT;  // 65536

typedef __bf16 bf16x8 __attribute__((ext_vector_type(8)));
typedef float  f32x4  __attribute__((ext_vector_type(4)));

// wcb[o][tap*64+c] = Wc[o][c*16+tap] (bf16);  w2t[c][c1] = W2[c1][c] (bf16)
__global__ void cvt_wts(const float* __restrict__ Wc, const float* __restrict__ W2,
                        __hip_bfloat16* __restrict__ wcb, __hip_bfloat16* __restrict__ w2t) {
    int i = blockIdx.x * 256 + threadIdx.x;
    if (i < COUT * KTOT) {
        int o = i >> 10, k = i & 1023, tap = k >> 6, c = k & 63;
        wcb[i] = __float2bfloat16(Wc[(size_t)o * KTOT + c * 16 + tap]);
    } else if (i < COUT * KTOT + CIN * CIN) {
        int m = i - COUT * KTOT;
        int c = m >> 6, c1 = m & 63;
        w2t[m] = __float2bfloat16(W2[c1 * CIN + c]);
    }
}

// ============================ K1: field kernel =============================
// Phases 1b+1c of the old fused kernel; A goes straight to global (128MB).
// No __syncthreads anywhere: 1b writes w for positions wv*4..wv*4+3 and 1c
// threads of the SAME wave read them (same-wave DS is in-order). LDS = 32KB
// (w only) -> higher blocks/CU; waves retire immediately after the gather.
__global__ __launch_bounds__(256, 2)
void k1_field(const float* __restrict__ x,  const float* __restrict__ r,
              const float* __restrict__ W1, const float* __restrict__ b1,
              const __hip_bfloat16* __restrict__ W2T, const float* __restrict__ b2,
              __hip_bfloat16* __restrict__ A, float* __restrict__ out)
{
    // Per position p (2 KiB region): w[row][col] at elem = row*64 + (col ^ ((row&7)<<2))
    __shared__ __hip_bfloat16 S[TW * 1024];   // 32,768 B

    const int t   = threadIdx.x;
    // XCD swizzle: grid 4096 = 8 XCDs x 512. Contiguous wid shares (b,ho)
    // x rows on one XCD's L2 (r7: FETCH -2.8x).
    const int bx  = blockIdx.x;
    const int wid = ((bx & 7) << 9) | (bx >> 3);   // bijective on [0,4096)
    const int wt  = wid & 31;
    const int ho  = (wid >> 5) & 31;
    const int b   = wid >> 10;
    const int wo0 = wt * TW;
    const int n_base = ((b * HOUT) + ho) * WOUT + wo0;   // global position base

    const float* rb = r + (size_t)b * HIN * WIN;

    // ---- output: r_center ----
    if (t < TW) {
        const int wo = wo0 + t;
        out[(size_t)B_*COUT*HOUT*WOUT + ((size_t)b*HOUT + ho)*WOUT + wo] =
            rb[(2*ho + 1)*WIN + (2*wo + 1)];
    }

    const int ln   = t & 63;
    const int wv   = t >> 6;
    const int lm   = ln & 15;
    const int quad = ln >> 4;

    const float AZI = 0.006135923151542565f;  // 2*pi/1024
    const float INC = 0.0073f;

    // ================= phase 1b: w = leaky(pe@W1+b1)@W2 + b2 via MFMA =================
    {
        bf16x8 bfr[4][2];
        float  b2v[4];
        #pragma unroll
        for (int nt = 0; nt < 4; ++nt) {
            #pragma unroll
            for (int ks = 0; ks < 2; ++ks)
                bfr[nt][ks] = *reinterpret_cast<const bf16x8*>(
                    W2T + (nt*16 + lm)*CIN + ks*32 + quad*8);
            b2v[nt] = b2[nt*16 + lm];
        }

        const int i_ = lm >> 2, j_ = lm & 3;
        const float di = (float)(i_ - 2), dj = (float)(j_ - 2);
        const float cA = cosf(AZI * dj), sA = sinf(AZI * dj);
        const float cI = cosf(INC * di), sI = sinf(INC * di);
        const int hsrc = (2*ho + j_ + 63) & 63;

        #pragma unroll
        for (int mt = 0; mt < 4; ++mt) {
            const int p  = wv*4 + mt;
            const int wo = wo0 + p;
            const int wsrc = 2*wo + i_ - 1;
            const bool inb = (unsigned)wsrc < (unsigned)WIN;
            const float rpv = inb ? rb[hsrc*WIN + wsrc] : 100.0f;
            const float rc  = rb[(2*ho + 1)*WIN + (2*wo + 1)];
            const float pe0 = rpv * cA * cI - rc;
            const float pe1 = rpv * cA * sI;
            const float pe2 = rpv * sA;

            bf16x8 af0, af1;
            #pragma unroll
            for (int ks = 0; ks < 2; ++ks) {
                const int cb = ks*32 + quad*8;
                #pragma unroll
                for (int j = 0; j < 8; ++j) {
                    const int c1 = cb + j;
                    float hv = fmaf(pe0, W1[c1],
                               fmaf(pe1, W1[CIN + c1],
                               fmaf(pe2, W1[2*CIN + c1], b1[c1])));
                    hv = (hv >= 0.0f) ? hv : 0.2f * hv;
                    __hip_bfloat16 hb = __float2bfloat16(hv);
                    if (ks == 0) af0[j] = *reinterpret_cast<__bf16*>(&hb);
                    else         af1[j] = *reinterpret_cast<__bf16*>(&hb);
                }
            }

            #pragma unroll
            for (int nt = 0; nt < 4; ++nt) {
                f32x4 acc = {b2v[nt], b2v[nt], b2v[nt], b2v[nt]};
                acc = __builtin_amdgcn_mfma_f32_16x16x32_bf16(af0, bfr[nt][0], acc, 0, 0, 0);
                acc = __builtin_amdgcn_mfma_f32_16x16x32_bf16(af1, bfr[nt][1], acc, 0, 0, 0);
                #pragma unroll
                for (int q = 0; q < 4; ++q) {
                    const int row = quad*4 + q;
                    S[p*1024 + row*64 + ((nt*16 + lm) ^ ((row & 7) << 2))] =
                        __float2bfloat16(acc[q]);
                }
            }
        }
    }

    // ================= phase 1c: A[n_base+p][tap*64+c] = w[tap][c] * x =================
    {
        const int p   = t >> 4;
        const int tap = t & 15;
        const int i_  = tap >> 2, j_ = tap & 3;
        const int hsrc = (2*ho + j_ + 63) & 63;
        const int wo   = wo0 + p;
        const int wsrc = 2*wo + i_ - 1;
        const bool inb = (unsigned)wsrc < (unsigned)WIN;

        const float* xb = x + (size_t)b*CIN*HIN*WIN + hsrc*WIN + wsrc;

        float xall[CIN];
        #pragma unroll
        for (int c = 0; c < CIN; ++c)
            xall[c] = inb ? xb[(size_t)c * HIN * WIN] : 0.0f;

        // read this row's w: logical 8B chunk u sits at physical chunk u^(tap&7)
        const int ws = tap & 7;
        uint2 wrow[16];
        const uint2* wp = reinterpret_cast<const uint2*>(S + p*1024 + tap*64);
        #pragma unroll
        for (int u = 0; u < 16; ++u) wrow[u] = wp[u ^ ws];

        uint4* Arow = reinterpret_cast<uint4*>(A + (size_t)(n_base + p)*KTOT + tap*64);

        #pragma unroll
        for (int g = 0; g < 8; ++g) {
            uint pk[4];
            #pragma unroll
            for (int pr = 0; pr < 4; ++pr) {
                const int c0 = g*8 + pr*2;
                const uint2 wv2 = wrow[c0 >> 2];
                const uint word = (c0 & 2) ? wv2.y : wv2.x;
                const float w0 = __uint_as_float(word << 16);
                const float w1 = __uint_as_float(word & 0xffff0000u);
                __hip_bfloat16 p0 = __float2bfloat16(w0 * xall[c0]);
                __hip_bfloat16 p1 = __float2bfloat16(w1 * xall[c0 + 1]);
                const uint lo = *reinterpret_cast<unsigned short*>(&p0);
                const uint hi = *reinterpret_cast<unsigned short*>(&p1);
                pk[pr] = lo | (hi << 16);
            }
            Arow[g] = make_uint4(pk[0], pk[1], pk[2], pk[3]);
        }
    }
}

// ============================ K2: GEMM kernel ==============================
// out[o][n] = bc[o] + sum_k WcB[o][k] * A[n][k].  M=128 (all o), tile N=64,
// K-steps of 64 (128B rows), double-buffered LDS, register-staged (issue
// loads for step ks+1 before MFMAs of ks -> HBM/L2 latency hides under MFMA).
// K-accumulation order identical to the old fused phase-2 -> bit-identical.
__global__ __launch_bounds__(256, 3)
void k2_gemm(const __hip_bfloat16* __restrict__ A, const __hip_bfloat16* __restrict__ WcB,
             const float* __restrict__ bc, float* __restrict__ out)
{
    __shared__ char S2[2][24576];   // per buf: WcT[128][128B] + AT[64][128B] = 24KB

    const int t  = threadIdx.x;
    const int n0 = blockIdx.x * 64;
    const int b  = n0 >> 14;
    const int ho = (n0 >> 9) & 31;
    const int wo0 = n0 & 511;

    const int ln = t & 63, wv = t >> 6, lm = ln & 15, quad = ln >> 4;

    // staging: 24KB = 6 chunks of 4KB; thread covers byte off = j*4096 + t*16
    const int koff = (t & 7) * 16;      // byte offset within a 128B k-row
    const char* gsrc[6];
    #pragma unroll
    for (int j = 0; j < 6; ++j) {
        const int rj = j*32 + (t >> 3);          // row 0..191
        gsrc[j] = (rj < 128)
            ? reinterpret_cast<const char*>(WcB) + (size_t)rj * (KTOT*2) + koff
            : reinterpret_cast<const char*>(A)   + (size_t)(n0 + rj - 128) * (KTOT*2) + koff;
    }
    const int soff = t * 16;

    uint4 sreg[6];
    f32x4 acc[2][4];
    #pragma unroll
    for (int og = 0; og < 2; ++og)
        #pragma unroll
        for (int ng = 0; ng < 4; ++ng)
            acc[og][ng] = f32x4{0.f, 0.f, 0.f, 0.f};

    // prologue: stage step 0 into buf0
    #pragma unroll
    for (int j = 0; j < 6; ++j)
        sreg[j] = *reinterpret_cast<const uint4*>(gsrc[j]);
    #pragma unroll
    for (int j = 0; j < 6; ++j)
        *reinterpret_cast<uint4*>(&S2[0][j*4096 + soff]) = sreg[j];
    __syncthreads();

    int cur = 0;
    for (int ks = 0; ks < 16; ++ks) {
        if (ks < 15) {
            #pragma unroll
            for (int j = 0; j < 6; ++j)
                sreg[j] = *reinterpret_cast<const uint4*>(gsrc[j] + (ks + 1) * 128);
        }

        const char* bufp = S2[cur];
        #pragma unroll
        for (int kc = 0; kc < 2; ++kc) {
            bf16x8 wcf[2], af[4];
            #pragma unroll
            for (int og = 0; og < 2; ++og)
                wcf[og] = *reinterpret_cast<const bf16x8*>(
                    bufp + (wv*32 + og*16 + lm)*128 + kc*64 + quad*16);
            #pragma unroll
            for (int ng = 0; ng < 4; ++ng)
                af[ng] = *reinterpret_cast<const bf16x8*>(
                    bufp + 16384 + (ng*16 + lm)*128 + kc*64 + quad*16);
            #pragma unroll
            for (int og = 0; og < 2; ++og)
                #pragma unroll
                for (int ng = 0; ng < 4; ++ng)
                    acc[og][ng] = __builtin_amdgcn_mfma_f32_16x16x32_bf16(
                        wcf[og], af[ng], acc[og][ng], 0, 0, 0);
        }
        __syncthreads();                 // all waves done reading buf[cur]
        if (ks < 15) {
            #pragma unroll
            for (int j = 0; j < 6; ++j)
                *reinterpret_cast<uint4*>(&S2[cur ^ 1][j*4096 + soff]) = sreg[j];
            __syncthreads();             // next buffer visible to all
        }
        cur ^= 1;
    }

    // epilogue
    #pragma unroll
    for (int og = 0; og < 2; ++og) {
        #pragma unroll
        for (int ng = 0; ng < 4; ++ng) {
            const int wo = wo0 + ng*16 + lm;
            #pragma unroll
            for (int q = 0; q < 4; ++q) {
                const int o = wv*32 + og*16 + quad*4 + q;
                out[(((size_t)b*COUT + o)*HOUT + ho)*WOUT + wo] = acc[og][ng][q] + bc[o];
            }
        }
    }
}

// ===================== fallback: proven r6 fused kernel =====================
__global__ __launch_bounds__(256, 3)
void fused_ccconv(const float* __restrict__ x,  const float* __restrict__ r,
                  const float* __restrict__ W1, const float* __restrict__ b1,
                  const __hip_bfloat16* __restrict__ W2T, const float* __restrict__ b2,
                  const __hip_bfloat16* __restrict__ WcB, const float* __restrict__ bc,
                  float* __restrict__ out)
{
    __shared__ __hip_bfloat16 S[TW * 1024];

    const int t   = threadIdx.x;
    const int bx  = blockIdx.x;
    const int wt  = bx & 31;
    const int ho  = (bx >> 5) & 31;
    const int b   = bx >> 10;
    const int wo0 = wt * TW;

    const float* rb = r + (size_t)b * HIN * WIN;

    if (t < TW) {
        const int wo = wo0 + t;
        out[(size_t)B_*COUT*HOUT*WOUT + ((size_t)b*HOUT + ho)*WOUT + wo] =
            rb[(2*ho + 1)*WIN + (2*wo + 1)];
    }

    const int ln   = t & 63;
    const int wv   = t >> 6;
    const int lm   = ln & 15;
    const int quad = ln >> 4;

    const float AZI = 0.006135923151542565f;
    const float INC = 0.0073f;

    {
        bf16x8 bfr[4][2];
        float  b2v[4];
        #pragma unroll
        for (int nt = 0; nt < 4; ++nt) {
            #pragma unroll
            for (int ks = 0; ks < 2; ++ks)
                bfr[nt][ks] = *reinterpret_cast<const bf16x8*>(
                    W2T + (nt*16 + lm)*CIN + ks*32 + quad*8);
            b2v[nt] = b2[nt*16 + lm];
        }

        const int i_ = lm >> 2, j_ = lm & 3;
        const float di = (float)(i_ - 2), dj = (float)(j_ - 2);
        const float cA = cosf(AZI * dj), sA = sinf(AZI * dj);
        const float cI = cosf(INC * di), sI = sinf(INC * di);
        const int hsrc = (2*ho + j_ + 63) & 63;

        #pragma unroll
        for (int mt = 0; mt < 4; ++mt) {
            const int p  = wv*4 + mt;
            const int wo = wo0 + p;
            const int wsrc = 2*wo + i_ - 1;
            const bool inb = (unsigned)wsrc < (unsigned)WIN;
            const float rpv = inb ? rb[hsrc*WIN + wsrc] : 100.0f;
            const float rc  = rb[(2*ho + 1)*WIN + (2*wo + 1)];
            const float pe0 = rpv * cA * cI - rc;
            const float pe1 = rpv * cA * sI;
            const float pe2 = rpv * sA;

            bf16x8 af0, af1;
            #pragma unroll
            for (int ks = 0; ks < 2; ++ks) {
                const int cb = ks*32 + quad*8;
                #pragma unroll
                for (int j = 0; j < 8; ++j) {
                    const int c1 = cb + j;
                    float hv = fmaf(pe0, W1[c1],
                               fmaf(pe1, W1[CIN + c1],
                               fmaf(pe2, W1[2*CIN + c1], b1[c1])));
                    hv = (hv >= 0.0f) ? hv : 0.2f * hv;
                    __hip_bfloat16 hb = __float2bfloat16(hv);
                    if (ks == 0) af0[j] = *reinterpret_cast<__bf16*>(&hb);
                    else         af1[j] = *reinterpret_cast<__bf16*>(&hb);
                }
            }

            #pragma unroll
            for (int nt = 0; nt < 4; ++nt) {
                f32x4 acc = {b2v[nt], b2v[nt], b2v[nt], b2v[nt]};
                acc = __builtin_amdgcn_mfma_f32_16x16x32_bf16(af0, bfr[nt][0], acc, 0, 0, 0);
                acc = __builtin_amdgcn_mfma_f32_16x16x32_bf16(af1, bfr[nt][1], acc, 0, 0, 0);
                #pragma unroll
                for (int q = 0; q < 4; ++q) {
                    const int row = quad*4 + q;
                    S[p*1024 + row*64 + ((nt*16 + lm) ^ ((row & 7) << 2))] =
                        __float2bfloat16(acc[q]);
                }
            }
        }
    }

    {
        const int p   = t >> 4;
        const int tap = t & 15;
        const int i_  = tap >> 2, j_ = tap & 3;
        const int hsrc = (2*ho + j_ + 63) & 63;
        const int wo   = wo0 + p;
        const int wsrc = 2*wo + i_ - 1;
        const bool inb = (unsigned)wsrc < (unsigned)WIN;

        const float* xb = x + (size_t)b*CIN*HIN*WIN + hsrc*WIN + wsrc;

        float xall[CIN];
        #pragma unroll
        for (int c = 0; c < CIN; ++c)
            xall[c] = inb ? xb[(size_t)c * HIN * WIN] : 0.0f;

        const int ws = tap & 7;
        uint2 wrow[16];
        const uint2* wp = reinterpret_cast<const uint2*>(S + p*1024 + tap*64);
        #pragma unroll
        for (int u = 0; u < 16; ++u) wrow[u] = wp[u ^ ws];

        const int swz = ((tap ^ p) & 7) << 4;
        char* Abase = reinterpret_cast<char*>(S + p*1024) + tap*128;

        #pragma unroll
        for (int g = 0; g < 8; ++g) {
            uint pk[4];
            #pragma unroll
            for (int pr = 0; pr < 4; ++pr) {
                const int c0 = g*8 + pr*2;
                const uint2 wv2 = wrow[c0 >> 2];
                const uint word = (c0 & 2) ? wv2.y : wv2.x;
                const float w0 = __uint_as_float(word << 16);
                const float w1 = __uint_as_float(word & 0xffff0000u);
                __hip_bfloat16 p0 = __float2bfloat16(w0 * xall[c0]);
                __hip_bfloat16 p1 = __float2bfloat16(w1 * xall[c0 + 1]);
                const uint lo = *reinterpret_cast<unsigned short*>(&p0);
                const uint hi = *reinterpret_cast<unsigned short*>(&p1);
                pk[pr] = lo | (hi << 16);
            }
            *reinterpret_cast<uint4*>(Abase + ((g*16) ^ swz)) =
                make_uint4(pk[0], pk[1], pk[2], pk[3]);
        }
    }

    __syncthreads();

    {
        const int o0 = wv * 32;
        const __hip_bfloat16* wcP0 = WcB + ((size_t)(o0 + lm)) * KTOT + quad*8;
        const __hip_bfloat16* wcP1 = wcP0 + (size_t)16 * KTOT;
        const char* aRow = reinterpret_cast<const char*>(S) + lm*2048;
        const int qoff = quad << 4;

        f32x4 acc0 = {0.f,0.f,0.f,0.f};
        f32x4 acc1 = {0.f,0.f,0.f,0.f};

        #pragma unroll 8
        for (int ks = 0; ks < KTOT/32; ++ks) {
            const int tap = ks >> 1;
            const int rem = ((ks & 1) << 6) + qoff;
            const bf16x8 af = *reinterpret_cast<const bf16x8*>(
                aRow + tap*128 + (rem ^ (((tap ^ lm) & 7) << 4)));
            const bf16x8 w0 = *reinterpret_cast<const bf16x8*>(wcP0 + ks*32);
            const bf16x8 w1 = *reinterpret_cast<const bf16x8*>(wcP1 + ks*32);
            acc0 = __builtin_amdgcn_mfma_f32_16x16x32_bf16(w0, af, acc0, 0, 0, 0);
            acc1 = __builtin_amdgcn_mfma_f32_16x16x32_bf16(w1, af, acc1, 0, 0, 0);
        }

        #pragma unroll
        for (int q = 0; q < 4; ++q) {
            const int oa = o0 + quad*4 + q;
            const int ob = oa + 16;
            out[(((size_t)b*COUT + oa)*HOUT + ho)*WOUT + wo0 + lm] = acc0[q] + bc[oa];
            out[(((size_t)b*COUT + ob)*HOUT + ho)*WOUT + wo0 + lm] = acc1[q] + bc[ob];
        }
    }
}

} // namespace

extern "C" void kernel_launch(void* const* d_in, const int* in_sizes, int n_in,
                              void* d_out, int out_size, void* d_ws, size_t ws_size,
                              hipStream_t stream) {
    const float* x  = (const float*)d_in[0];
    const float* r  = (const float*)d_in[1];
    const float* W1 = (const float*)d_in[2];
    const float* b1 = (const float*)d_in[3];
    const float* W2 = (const float*)d_in[4];
    const float* b2 = (const float*)d_in[5];
    const float* Wc = (const float*)d_in[6];
    const float* bc = (const float*)d_in[7];
    float* out = (float*)d_out;

    __hip_bfloat16* wcb = (__hip_bfloat16*)d_ws;                       // 256 KB
    __hip_bfloat16* w2t = (__hip_bfloat16*)((char*)d_ws + 262144);     // 8 KB
    __hip_bfloat16* A   = (__hip_bfloat16*)((char*)d_ws + 270336);     // 128 MB

    const size_t NEED = 270336 + (size_t)NPOS * KTOT * 2;

    const int ntot = COUT*KTOT + CIN*CIN;   // 135168
    hipLaunchKernelGGL(cvt_wts, dim3((ntot + 255)/256), dim3(256), 0, stream,
                       Wc, W2, wcb, w2t);

    if (ws_size >= NEED) {
        hipLaunchKernelGGL(k1_field, dim3(B_ * HOUT * (WOUT / TW)), dim3(256), 0, stream,
                           x, r, W1, b1, w2t, b2, A, out);
        hipLaunchKernelGGL(k2_gemm, dim3(NPOS / 64), dim3(256), 0, stream,
                           A, wcb, bc, out);
    } else {
        hipLaunchKernelGGL(fused_ccconv, dim3(B_ * HOUT * (WOUT / TW)), dim3(256), 0, stream,
                           x, r, W1, b1, w2t, b2, wcb, bc, out);
    }
}

// Round 9
// 309.105 us; speedup vs baseline: 1.1093x; 1.1093x over previous
//
#include <hip/hip_runtime.h>
#include <hip/hip_bf16.h>

namespace {

constexpr int B_   = 4;
constexpr int CIN  = 64;
constexpr int COUT = 128;
constexpr int HIN  = 64,  WIN  = 1024;
constexpr int HOUT = 32,  WOUT = 512;
constexpr int TW   = 16;        // wo positions per block
constexpr int KTOT = CIN * 16;  // 1024
constexpr int XW   = 40;        // staged tile width (covers wloc in [3,35])

typedef __bf16 bf16x8 __attribute__((ext_vector_type(8)));
typedef float  f32x4  __attribute__((ext_vector_type(4)));

// wcb[o][tap*64+c] = Wc[o][c*16+tap] (bf16);  w2t[c][c1] = W2[c1][c] (bf16)
__global__ void cvt_wts(const float* __restrict__ Wc, const float* __restrict__ W2,
                        __hip_bfloat16* __restrict__ wcb, __hip_bfloat16* __restrict__ w2t) {
    int i = blockIdx.x * 256 + threadIdx.x;
    if (i < COUT * KTOT) {
        int o = i >> 10, k = i & 1023, tap = k >> 6, c = k & 63;
        wcb[i] = __float2bfloat16(Wc[(size_t)o * KTOT + c * 16 + tap]);
    } else if (i < COUT * KTOT + CIN * CIN) {
        int m = i - COUT * KTOT;
        int c = m >> 6, c1 = m & 63;
        w2t[m] = __float2bfloat16(W2[c1 * CIN + c]);
    }
}

// r0-r8 established: time invariant under conflicts/VGPR/occupancy/FETCH/tile/
// swizzle; r8 split isolated gather+MLP at 143us with all pipes idle. Model:
// the serialized resource is the vector-mem ADDRESS path — 64 scattered 4B
// x-loads + 8 scattered r-loads per thread, each wave-instr touching 16-48
// cache lines. Fix: coalesced LDS staging of the x/r tiles (40KB+640B), then
// phase 1b/1c read LDS (~2-way conflicts = free). Scattered requests/block
// drop ~25x. Everything else is the proven r6 structure.
__global__ __launch_bounds__(256, 3)
void fused_ccconv(const float* __restrict__ x,  const float* __restrict__ r,
                  const float* __restrict__ W1, const float* __restrict__ b1,
                  const __hip_bfloat16* __restrict__ W2T, const float* __restrict__ b2,
                  const __hip_bfloat16* __restrict__ WcB, const float* __restrict__ bc,
                  float* __restrict__ out)
{
    // S (per position p, 2KiB): phase 1b writes w[row][col] at
    //   elem = row*64 + (col ^ ((row&7)<<2));  phase 1c overwrites with A
    //   at byte = tap*128 + (chunk16 ^ ((tap^p)&7))*16. Same-wave DS in-order.
    __shared__ __hip_bfloat16 S[TW * 1024];     // 32,768 B
    __shared__ float xs[CIN * 4 * XW];          // 40,960 B  x tile [c][hh][XW]
    __shared__ float rs[4 * XW];                //    640 B  r tile [hh][XW]

    const int t   = threadIdx.x;
    // XCD swizzle: grid 4096 = 8 XCDs x 512; contiguous wid shares (b,ho) rows
    // on one XCD's L2 (r7: FETCH -2.8x).
    const int bx  = blockIdx.x;
    const int wid = ((bx & 7) << 9) | (bx >> 3);   // bijective on [0,4096)
    const int wt  = wid & 31;
    const int ho  = (wid >> 5) & 31;
    const int b   = wid >> 10;
    const int wo0 = wt * TW;
    const int w0a = 2*wo0 - 4;                  // aligned tile origin (mult of 4)

    const float* rb = r + (size_t)b * HIN * WIN;

    // ================= stage x and r tiles (coalesced float4) =================
    {
        const int c  = t >> 2;                  // 0..63
        const int hh = t & 3;                   // row offset-1..+2
        const int hsrc = (2*ho + hh + 63) & 63;
        const float* xrow = x + (size_t)b*CIN*HIN*WIN + (size_t)c*HIN*WIN
                              + (size_t)hsrc*WIN;
        float* xd = xs + (c*4 + hh) * XW;
        #pragma unroll
        for (int k = 0; k < 10; ++k) {
            const int w = w0a + 4*k;            // float4 never straddles 0/1024
            float4 v;
            if ((unsigned)w < (unsigned)WIN) v = *reinterpret_cast<const float4*>(xrow + w);
            else                             v = make_float4(0.f, 0.f, 0.f, 0.f);
            *reinterpret_cast<float4*>(xd + 4*k) = v;
        }
        if (t < 40) {
            const int hh2 = t / 10, k2 = t % 10;
            const int hsrc2 = (2*ho + hh2 + 63) & 63;
            const int w = w0a + 4*k2;
            float4 v;
            if ((unsigned)w < (unsigned)WIN)
                v = *reinterpret_cast<const float4*>(rb + (size_t)hsrc2*WIN + w);
            else
                v = make_float4(100.f, 100.f, 100.f, 100.f);   // r pad value
            *reinterpret_cast<float4*>(rs + hh2*XW + 4*k2) = v;
        }
    }
    __syncthreads();

    // ---- output 1: r_center (row 2ho+1 = hh2, col 2wo+1 -> wloc 2p+5) ----
    if (t < TW)
        out[(size_t)B_*COUT*HOUT*WOUT + ((size_t)b*HOUT + ho)*WOUT + wo0 + t] =
            rs[2*XW + 2*t + 5];

    const int ln   = t & 63;
    const int wv   = t >> 6;
    const int lm   = ln & 15;
    const int quad = ln >> 4;

    const float AZI = 0.006135923151542565f;  // 2*pi/1024
    const float INC = 0.0073f;

    // ================= phase 1b: w = leaky(pe@W1+b1)@W2 + b2 via MFMA =================
    {
        bf16x8 bfr[4][2];
        float  b2v[4];
        #pragma unroll
        for (int nt = 0; nt < 4; ++nt) {
            #pragma unroll
            for (int ks = 0; ks < 2; ++ks)
                bfr[nt][ks] = *reinterpret_cast<const bf16x8*>(
                    W2T + (nt*16 + lm)*CIN + ks*32 + quad*8);
            b2v[nt] = b2[nt*16 + lm];
        }

        const int i_ = lm >> 2, j_ = lm & 3;
        const float di = (float)(i_ - 2), dj = (float)(j_ - 2);
        const float cA = cosf(AZI * dj), sA = sinf(AZI * dj);
        const float cI = cosf(INC * di), sI = sinf(INC * di);

        #pragma unroll
        for (int mt = 0; mt < 4; ++mt) {
            const int p  = wv*4 + mt;
            // rpv: row j_, wloc = 2p + i_ + 3 (OOB 100.0 baked in at staging)
            const float rpv = rs[j_*XW + 2*p + i_ + 3];
            const float rc  = rs[2*XW + 2*p + 5];
            const float pe0 = rpv * cA * cI - rc;
            const float pe1 = rpv * cA * sI;
            const float pe2 = rpv * sA;

            bf16x8 af0, af1;
            #pragma unroll
            for (int ks = 0; ks < 2; ++ks) {
                const int cb = ks*32 + quad*8;
                #pragma unroll
                for (int j = 0; j < 8; ++j) {
                    const int c1 = cb + j;
                    float hv = fmaf(pe0, W1[c1],
                               fmaf(pe1, W1[CIN + c1],
                               fmaf(pe2, W1[2*CIN + c1], b1[c1])));
                    hv = (hv >= 0.0f) ? hv : 0.2f * hv;
                    __hip_bfloat16 hb = __float2bfloat16(hv);
                    if (ks == 0) af0[j] = *reinterpret_cast<__bf16*>(&hb);
                    else         af1[j] = *reinterpret_cast<__bf16*>(&hb);
                }
            }

            #pragma unroll
            for (int nt = 0; nt < 4; ++nt) {
                f32x4 acc = {b2v[nt], b2v[nt], b2v[nt], b2v[nt]};
                acc = __builtin_amdgcn_mfma_f32_16x16x32_bf16(af0, bfr[nt][0], acc, 0, 0, 0);
                acc = __builtin_amdgcn_mfma_f32_16x16x32_bf16(af1, bfr[nt][1], acc, 0, 0, 0);
                #pragma unroll
                for (int q = 0; q < 4; ++q) {
                    const int row = quad*4 + q;
                    S[p*1024 + row*64 + ((nt*16 + lm) ^ ((row & 7) << 2))] =
                        __float2bfloat16(acc[q]);
                }
            }
        }
    }

    // ================= phase 1c: A[p][tap*64+c] = w[tap][c] * x (x from LDS) =========
    {
        const int p   = t >> 4;
        const int tap = t & 15;
        const int i_  = tap >> 2, j_ = tap & 3;
        const int wloc = 2*p + i_ + 3;          // OOB zeros baked in at staging

        // x values from the staged tile: stride 4*XW floats per channel,
        // ~2-way bank aliasing across the wave (free, m136)
        float xall[CIN];
        #pragma unroll
        for (int c = 0; c < CIN; ++c)
            xall[c] = xs[(c*4 + j_)*XW + wloc];

        // read this row's w: logical 8B chunk u at physical chunk u^(tap&7)
        const int ws = tap & 7;
        uint2 wrow[16];
        const uint2* wp = reinterpret_cast<const uint2*>(S + p*1024 + tap*64);
        #pragma unroll
        for (int u = 0; u < 16; ++u) wrow[u] = wp[u ^ ws];

        // A-writes: 16B chunk g -> physical chunk g ^ ((tap^p)&7)
        const int swz = ((tap ^ p) & 7) << 4;
        char* Abase = reinterpret_cast<char*>(S + p*1024) + tap*128;

        #pragma unroll
        for (int g = 0; g < 8; ++g) {
            uint pk[4];
            #pragma unroll
            for (int pr = 0; pr < 4; ++pr) {
                const int c0 = g*8 + pr*2;
                const uint2 wv2 = wrow[c0 >> 2];
                const uint word = (c0 & 2) ? wv2.y : wv2.x;
                const float w0 = __uint_as_float(word << 16);
                const float w1 = __uint_as_float(word & 0xffff0000u);
                __hip_bfloat16 p0 = __float2bfloat16(w0 * xall[c0]);
                __hip_bfloat16 p1 = __float2bfloat16(w1 * xall[c0 + 1]);
                const uint lo = *reinterpret_cast<unsigned short*>(&p0);
                const uint hi = *reinterpret_cast<unsigned short*>(&p1);
                pk[pr] = lo | (hi << 16);
            }
            *reinterpret_cast<uint4*>(Abase + ((g*16) ^ swz)) =
                make_uint4(pk[0], pk[1], pk[2], pk[3]);
        }
    }

    __syncthreads();

    // ================= phase 2: out[o][p] = bc[o] + sum_k Wc[o][k']*A[p][k'] =========
    {
        const int o0 = wv * 32;
        const __hip_bfloat16* wcP0 = WcB + ((size_t)(o0 + lm)) * KTOT + quad*8;
        const __hip_bfloat16* wcP1 = wcP0 + (size_t)16 * KTOT;
        const char* aRow = reinterpret_cast<const char*>(S) + lm*2048;
        const int qoff = quad << 4;

        f32x4 acc0 = {0.f,0.f,0.f,0.f};
        f32x4 acc1 = {0.f,0.f,0.f,0.f};

        #pragma unroll 8
        for (int ks = 0; ks < KTOT/32; ++ks) {
            const int tap = ks >> 1;
            const int rem = ((ks & 1) << 6) + qoff;
            const bf16x8 af = *reinterpret_cast<const bf16x8*>(
                aRow + tap*128 + (rem ^ (((tap ^ lm) & 7) << 4)));  // matches writer
            const bf16x8 w0 = *reinterpret_cast<const bf16x8*>(wcP0 + ks*32);
            const bf16x8 w1 = *reinterpret_cast<const bf16x8*>(wcP1 + ks*32);
            acc0 = __builtin_amdgcn_mfma_f32_16x16x32_bf16(w0, af, acc0, 0, 0, 0);
            acc1 = __builtin_amdgcn_mfma_f32_16x16x32_bf16(w1, af, acc1, 0, 0, 0);
        }

        #pragma unroll
        for (int q = 0; q < 4; ++q) {
            const int oa = o0 + quad*4 + q;
            const int ob = oa + 16;
            out[(((size_t)b*COUT + oa)*HOUT + ho)*WOUT + wo0 + lm] = acc0[q] + bc[oa];
            out[(((size_t)b*COUT + ob)*HOUT + ho)*WOUT + wo0 + lm] = acc1[q] + bc[ob];
        }
    }
}

} // namespace

extern "C" void kernel_launch(void* const* d_in, const int* in_sizes, int n_in,
                              void* d_out, int out_size, void* d_ws, size_t ws_size,
                              hipStream_t stream) {
    const float* x  = (const float*)d_in[0];
    const float* r  = (const float*)d_in[1];
    const float* W1 = (const float*)d_in[2];
    const float* b1 = (const float*)d_in[3];
    const float* W2 = (const float*)d_in[4];
    const float* b2 = (const float*)d_in[5];
    const float* Wc = (const float*)d_in[6];
    const float* bc = (const float*)d_in[7];
    float* out = (float*)d_out;

    __hip_bfloat16* wcb = (__hip_bfloat16*)d_ws;                       // 256 KB
    __hip_bfloat16* w2t = (__hip_bfloat16*)((char*)d_ws + 262144);     // 8 KB

    const int ntot = COUT*KTOT + CIN*CIN;   // 135168
    hipLaunchKernelGGL(cvt_wts, dim3((ntot + 255)/256), dim3(256), 0, stream,
                       Wc, W2, wcb, w2t);

    dim3 grid(B_ * HOUT * (WOUT / TW));   // 4096
    dim3 block(256);
    hipLaunchKernelGGL(fused_ccconv, grid, block, 0, stream,
                       x, r, W1, b1, w2t, b2, wcb, bc, out);
}